// Round 9
// baseline (250.567 us; speedup 1.0000x reference)
//
#include <hip/hip_runtime.h>
#include <hip/hip_bf16.h>

typedef short short8 __attribute__((ext_vector_type(8)));
typedef short short4v __attribute__((ext_vector_type(4)));
typedef float floatx4 __attribute__((ext_vector_type(4)));

constexpr int BB  = 16;
constexpr int NN  = 256;
constexpr int DD  = 1024;
constexpr int HHc = 16;
constexpr int DKc = 64;

constexpr float LAM_ATT  = 0.33f;
constexpr float LAM_DIST = 0.33f;
constexpr float LAM_ADJ  = 0.34f;
constexpr float EPS_     = 1e-6f;

__device__ __forceinline__ float loadf(const void* p, size_t i, int f32) {
    return f32 ? ((const float*)p)[i] : (float)((const __hip_bfloat16*)p)[i];
}

__device__ __forceinline__ short8 load8_bf16(const void* p, size_t i, int f32) {
    if (f32) {
        const float4* q = (const float4*)((const float*)p + i);
        float4 a = q[0], b = q[1];
        short8 r;
        r[0] = (short)__bfloat16_as_ushort(__float2bfloat16(a.x));
        r[1] = (short)__bfloat16_as_ushort(__float2bfloat16(a.y));
        r[2] = (short)__bfloat16_as_ushort(__float2bfloat16(a.z));
        r[3] = (short)__bfloat16_as_ushort(__float2bfloat16(a.w));
        r[4] = (short)__bfloat16_as_ushort(__float2bfloat16(b.x));
        r[5] = (short)__bfloat16_as_ushort(__float2bfloat16(b.y));
        r[6] = (short)__bfloat16_as_ushort(__float2bfloat16(b.z));
        r[7] = (short)__bfloat16_as_ushort(__float2bfloat16(b.w));
        return r;
    }
    return *(const short8*)((const __hip_bfloat16*)p + i);
}

// Async global->LDS, 16B per lane. LDS dest = wave-uniform base + lane*16.
__device__ __forceinline__ void gl_lds16(const void* g, void* l) {
    __builtin_amdgcn_global_load_lds(
        (const __attribute__((address_space(1))) void*)g,
        (__attribute__((address_space(3))) void*)l, 16, 0, 0);
}

// ---------------------------------------------------------------------------
// Dtype detection + canonical mask (verified working; do not touch)
// ---------------------------------------------------------------------------
__global__ __launch_bounds__(256) void detect_kernel(
    const void* __restrict__ query, const void* __restrict__ maskraw,
    int* __restrict__ mask_canon, int* __restrict__ flags)
{
    __shared__ int s_f32;
    const int tid = threadIdx.x;
    if (tid == 0) s_f32 = 0;
    __syncthreads();

    const unsigned short* qh = (const unsigned short*)query;
    int hit = 0;
    for (int i = tid; i < 16384; i += 256)
        if ((qh[i] & 0x7F80u) == 0x7F80u) hit = 1;
    if (hit) atomicOr(&s_f32, 1);
    __syncthreads();
    if (tid == 0) flags[0] = s_f32;

    unsigned int w0 = ((const unsigned int*)maskraw)[0];
    int mdt = (w0 == 1u) ? 0 : ((w0 == 0x3F800000u) ? 1 : 2);

    for (int i = tid; i < BB * NN; i += 256) {
        int v;
        if (mdt == 0)      v = (((const int*)maskraw)[i] != 0);
        else if (mdt == 1) v = ((((const unsigned int*)maskraw)[i] & 0x7FFFFFFFu) != 0u);
        else               v = ((((const unsigned short*)maskraw)[i] & 0x7FFFu) != 0);
        mask_canon[i] = v;
    }
}

// ---------------------------------------------------------------------------
// prep_mega: one dispatch for W-transpose, bias, Mmix, activation convert.
// ---------------------------------------------------------------------------
__global__ __launch_bounds__(256) void prep_mega(
    const void* query, const void* key, const void* value,
    const void* adj, const void* dist,
    const void* W0, const void* W1, const void* W2, const void* W3,
    const void* b0, const void* b1, const void* b2, const void* b3,
    const int* __restrict__ mask_canon, const int* __restrict__ flags,
    __hip_bfloat16* __restrict__ Wt_all, __hip_bfloat16* __restrict__ bias_all,
    __hip_bfloat16* __restrict__ Mmix,
    __hip_bfloat16* __restrict__ Qc, __hip_bfloat16* __restrict__ Kc,
    __hip_bfloat16* __restrict__ Vc)
{
    __shared__ __hip_bfloat16 T[64][66];
    const int f32 = flags[0];
    const int bid = blockIdx.x;
    const int tid = threadIdx.x;

    if (bid < 1024) {
        const int z = bid >> 8, rem = bid & 255;
        const int y = rem >> 4, x = rem & 15;
        const void* W = (z == 0) ? W0 : (z == 1) ? W1 : (z == 2) ? W2 : W3;
        __hip_bfloat16* Wt = Wt_all + (size_t)z * DD * DD;
        const int k0 = y * 64, n0 = x * 64;
        #pragma unroll
        for (int i = 0; i < 16; i++) {
            int e = tid + i * 256;
            int kr = e >> 6, nc = e & 63;
            T[kr][nc] = __float2bfloat16(loadf(W, (size_t)(k0 + kr) * DD + n0 + nc, f32));
        }
        __syncthreads();
        #pragma unroll
        for (int i = 0; i < 16; i++) {
            int e = tid + i * 256;
            int nr = e >> 6, kc = e & 63;
            Wt[(size_t)(n0 + nr) * DD + k0 + kc] = T[kc][nr];
        }
    } else if (bid < 1028) {
        const int z = bid - 1024;
        const void* s = (z == 0) ? b0 : (z == 1) ? b1 : (z == 2) ? b2 : b3;
        #pragma unroll
        for (int i = 0; i < 4; i++) {
            int idx = tid + i * 256;
            bias_all[z * DD + idx] = __float2bfloat16(loadf(s, idx, f32));
        }
    } else if (bid < 2052) {
        const int idx = bid - 1028;
        const int wave = tid >> 6, lane = tid & 63;
        const int b = idx >> 6;
        const int q = (idx & 63) * 4 + wave;
        const size_t rowOff = ((size_t)b * NN + q) * NN;
        const int c0 = lane * 4;

        float a[4], nd[4];
        int msk[4];
        #pragma unroll
        for (int i = 0; i < 4; i++) {
            a[i]   = loadf(adj, rowOff + c0 + i, f32);
            msk[i] = mask_canon[b * NN + c0 + i];
            nd[i]  = msk[i] ? -loadf(dist, rowOff + c0 + i, f32) : -3.0e38f;
        }

        float asum = a[0] + a[1] + a[2] + a[3];
        #pragma unroll
        for (int off = 1; off < 64; off <<= 1) asum += __shfl_xor(asum, off);

        float mx = fmaxf(fmaxf(nd[0], nd[1]), fmaxf(nd[2], nd[3]));
        #pragma unroll
        for (int off = 1; off < 64; off <<= 1) mx = fmaxf(mx, __shfl_xor(mx, off));

        float e[4];
        float esum = 0.f;
        #pragma unroll
        for (int i = 0; i < 4; i++) {
            e[i] = msk[i] ? __expf(nd[i] - mx) : 0.f;
            esum += e[i];
        }
        #pragma unroll
        for (int off = 1; off < 64; off <<= 1) esum += __shfl_xor(esum, off);

        const float ia = 1.f / (asum + EPS_);
        const float ie = 1.f / fmaxf(esum, 1e-30f);
        __hip_bfloat16 out[4];
        #pragma unroll
        for (int i = 0; i < 4; i++)
            out[i] = __float2bfloat16(LAM_DIST * e[i] * ie + LAM_ADJ * a[i] * ia);
        *(short4v*)((unsigned short*)Mmix + rowOff + c0) = *(short4v*)out;
    } else {
        const int idx = bid - 2052;
        const int y = idx >> 11, xb = idx & 2047;
        const void* src = (y == 0) ? query : (y == 1) ? key : value;
        __hip_bfloat16* dst = (y == 0) ? Qc : (y == 1) ? Kc : Vc;
        size_t off = ((size_t)xb * 256 + tid) * 8;
        *(short8*)(dst + off) = load8_bf16(src, off, f32);
    }
}

// ---------------------------------------------------------------------------
// MFMA GEMM core, BK=32, DOUBLE-BUFFERED LDS, one barrier per K-iter.
// Loop shape: barrier -> prefetch(next tile) -> compute(current tile).
// The compiler's vmcnt(0)-before-s_barrier then waits on a DMA issued one
// full compute phase earlier (latency hidden), not the just-issued one.
// Buffer reuse is safe: prefetch target = buffer consumed 2 iters ago, and
// every wave passed the barrier after finishing that compute.
// ---------------------------------------------------------------------------
template<int MSUB, int NSUB>
__device__ __forceinline__ void gemm_core(
    const __hip_bfloat16* __restrict__ A,
    const __hip_bfloat16* __restrict__ Wt,
    const __hip_bfloat16* __restrict__ bias,
    void* __restrict__ C,
    int c_f32, int rowBase, int colBase,
    __hip_bfloat16* __restrict__ Vt, int writeVt)
{
    constexpr int BM = 32 * MSUB, BN = 32 * NSUB;
    __shared__ __hip_bfloat16 As[2][BM][32];
    __shared__ __hip_bfloat16 Ws[2][BN][32];

    const int tid  = threadIdx.x;
    const int wave = tid >> 6, lane = tid & 63;
    const int quad = lane >> 4, cl = lane & 15;
    const int wm = (wave >> 1) * (16 * MSUB), wn = (wave & 1) * (16 * NSUB);
    const int lr = lane >> 2;            // row within 16-row DMA chunk
    const int lg = (lane & 3) ^ (lr & 3);// swizzled global chunk for this lane

    floatx4 acc[MSUB][NSUB];
    #pragma unroll
    for (int i = 0; i < MSUB; i++)
        #pragma unroll
        for (int j = 0; j < NSUB; j++)
            acc[i][j] = (floatx4){0.f, 0.f, 0.f, 0.f};

    auto stage = [&](int buf, int k0) {
        #pragma unroll
        for (int j = 0; j < MSUB / 2; j++) {
            int r0 = (wave * (MSUB / 2) + j) * 16;
            gl_lds16(A + (size_t)(rowBase + r0 + lr) * DD + k0 + lg * 8,
                     &As[buf][r0][0]);
        }
        #pragma unroll
        for (int j = 0; j < NSUB / 2; j++) {
            int r0 = (wave * (NSUB / 2) + j) * 16;
            gl_lds16(Wt + (size_t)(colBase + r0 + lr) * DD + k0 + lg * 8,
                     &Ws[buf][r0][0]);
        }
    };

    stage(0, 0);                          // prologue

    constexpr int ITERS = DD / 32;        // 32
    for (int it = 0; it < ITERS; ++it) {
        const int cur = it & 1;
        __syncthreads();                  // waits tile-it DMA + prev compute
        if (it + 1 < ITERS)
            stage(cur ^ 1, (it + 1) * 32);// in flight during compute below

        short8 af[MSUB], bfr[NSUB];
        #pragma unroll
        for (int ms = 0; ms < MSUB; ms++) {
            int row = wm + ms * 16 + cl;
            af[ms] = *(const short8*)&As[cur][row][(quad ^ (row & 3)) * 8];
        }
        #pragma unroll
        for (int ns = 0; ns < NSUB; ns++) {
            int row = wn + ns * 16 + cl;
            bfr[ns] = *(const short8*)&Ws[cur][row][(quad ^ (row & 3)) * 8];
        }
        #pragma unroll
        for (int ms = 0; ms < MSUB; ms++)
            #pragma unroll
            for (int ns = 0; ns < NSUB; ns++)
                acc[ms][ns] = __builtin_amdgcn_mfma_f32_16x16x32_bf16(
                    af[ms], bfr[ns], acc[ms][ns], 0, 0, 0);
    }

    // D row = quad*4+reg, col = lane&15 (verified m89/m91)
    #pragma unroll
    for (int ns = 0; ns < NSUB; ns++) {
        int col = colBase + wn + ns * 16 + cl;
        float bc = (float)bias[col];
        if (writeVt) {
            int h = col >> 6, dk = col & 63;
            #pragma unroll
            for (int ms = 0; ms < MSUB; ms++) {
                int row0 = rowBase + wm + ms * 16 + quad * 4;
                int b = row0 >> 8, tok = row0 & 255;
                __hip_bfloat16 pk[4];
                #pragma unroll
                for (int r = 0; r < 4; r++)
                    pk[r] = __float2bfloat16(acc[ms][ns][r] + bc);
                *(short4v*)&Vt[((size_t)((b * HHc + h) * DKc + dk)) * NN + tok] =
                    *(short4v*)pk;
            }
        } else {
            #pragma unroll
            for (int ms = 0; ms < MSUB; ms++) {
                #pragma unroll
                for (int r = 0; r < 4; r++) {
                    int row = rowBase + wm + ms * 16 + quad * 4 + r;
                    float v = acc[ms][ns][r] + bc;
                    size_t idx = (size_t)row * DD + col;
                    if (c_f32) ((float*)C)[idx] = v;
                    else ((__hip_bfloat16*)C)[idx] = __float2bfloat16(v);
                }
            }
        }
    }
}

// Fused Q/K/V projection, XCD-swizzled. z==2 (V) writes Vt (fused transpose).
__global__ __launch_bounds__(256) void qkv_mfma(
    const __hip_bfloat16* __restrict__ Qc, const __hip_bfloat16* __restrict__ Kc,
    const __hip_bfloat16* __restrict__ Vc,
    const __hip_bfloat16* __restrict__ Wt_all,
    const __hip_bfloat16* __restrict__ bias_all,
    __hip_bfloat16* Qp, __hip_bfloat16* Kp, __hip_bfloat16* Vt)
{
    const int bid = blockIdx.x;
    const int xcd = bid & 7, s = bid >> 3;       // s in [0,96)
    const int x = s & 7;                          // col panel
    const int t = s >> 3;                         // [0,12)
    const int y = xcd + 8 * (t & 3);              // row panel [0,32)
    const int z = t >> 2;                         // matrix [0,3)

    const __hip_bfloat16* A = (z == 0) ? Qc : (z == 1) ? Kc : Vc;
    __hip_bfloat16* C = (z == 0) ? Qp : Kp;
    gemm_core<4, 4>(A, Wt_all + (size_t)z * DD * DD, bias_all + z * DD, C,
                    0, y * 128, x * 128, Vt, z == 2);
}

// Output projection: 128x64 tiles, 512 blocks, XCD-swizzled.
__global__ __launch_bounds__(256) void out_mfma(
    const __hip_bfloat16* __restrict__ X,
    const __hip_bfloat16* __restrict__ Wt,
    const __hip_bfloat16* __restrict__ bias,
    void* C, const int* __restrict__ flags)
{
    const int bid = blockIdx.x;
    const int xcd = bid & 7, s = bid >> 3;       // s in [0,64)
    const int x = s & 15;                         // col panel (BN=64)
    const int y = xcd + 8 * (s >> 4);             // row panel [0,32)
    gemm_core<4, 2>(X, Wt, bias, C, flags[0], y * 128, x * 64, nullptr, 0);
}

// ---------------------------------------------------------------------------
// MFMA attention (validated round 5/6 structure, unchanged).
// ---------------------------------------------------------------------------
__global__ __launch_bounds__(256) void attn_mfma(
    const __hip_bfloat16* __restrict__ Qp,
    const __hip_bfloat16* __restrict__ Kp,
    const __hip_bfloat16* __restrict__ Vt,
    const __hip_bfloat16* __restrict__ Mmix,
    const int* __restrict__ mask_canon,
    __hip_bfloat16* __restrict__ X)
{
    __shared__ __hip_bfloat16 smem[16896];      // max(Ks 256*64, Ps 4*16*264)
    __hip_bfloat16* Ks = smem;                  // [256][64], kc swizzled
    __hip_bfloat16* Ps = smem;                  // [4][16][264]

    const int bid = blockIdx.x;
    const int xcd = bid & 7, sdec = bid >> 3;     // [0,128)
    const int qt = sdec & 3;
    const int hb = xcd + 8 * (sdec >> 2);         // [0,256)
    const int h = hb & 15, b = hb >> 4;

    const int tid = threadIdx.x;
    const int wave = tid >> 6, lane = tid & 63;
    const int quad = lane >> 4, cl = lane & 15;
    const int q0 = qt * 64 + wave * 16;

    const size_t qoff = ((size_t)(b * NN + q0 + cl)) * DD + h * DKc + quad * 8;
    short8 aq0 = *(const short8*)(Qp + qoff);
    short8 aq1 = *(const short8*)(Qp + qoff + 32);

    #pragma unroll
    for (int j = 0; j < 8; j++) {
        int cbase = (j * 4 + wave) * 64;          // wave-uniform
        int c = cbase + lane;
        int tok = c >> 3, kc = c & 7;
        gl_lds16(Kp + ((size_t)(b * NN + tok)) * DD + h * DKc + ((kc ^ (tok & 7)) * 8),
                 (char*)Ks + (size_t)cbase * 16);
    }

    int msk[16];
    #pragma unroll
    for (int ns = 0; ns < 16; ns++)
        msk[ns] = mask_canon[b * NN + ns * 16 + cl];

    __syncthreads();   // K staging complete

    floatx4 accS[16];
    #pragma unroll
    for (int ns = 0; ns < 16; ns++) accS[ns] = (floatx4){0.f, 0.f, 0.f, 0.f};
    #pragma unroll
    for (int ns = 0; ns < 16; ns++) {
        int tok = ns * 16 + cl;
        const __hip_bfloat16* row = Ks + tok * 64;
        short8 bk0 = *(const short8*)(row + ((quad ^ (tok & 7)) * 8));
        short8 bk1 = *(const short8*)(row + (((quad + 4) ^ (tok & 7)) * 8));
        accS[ns] = __builtin_amdgcn_mfma_f32_16x16x32_bf16(aq0, bk0, accS[ns], 0, 0, 0);
        accS[ns] = __builtin_amdgcn_mfma_f32_16x16x32_bf16(aq1, bk1, accS[ns], 0, 0, 0);
    }
    __syncthreads();   // Ks reads done before Ps overwrites union

    #pragma unroll
    for (int r = 0; r < 4; r++) {
        float s[16];
        #pragma unroll
        for (int ns = 0; ns < 16; ns++)
            s[ns] = msk[ns] ? accS[ns][r] * 0.125f : -1e12f;
        float mx = s[0];
        #pragma unroll
        for (int ns = 1; ns < 16; ns++) mx = fmaxf(mx, s[ns]);
        mx = fmaxf(mx, __shfl_xor(mx, 1));
        mx = fmaxf(mx, __shfl_xor(mx, 2));
        mx = fmaxf(mx, __shfl_xor(mx, 4));
        mx = fmaxf(mx, __shfl_xor(mx, 8));
        float e[16], sum = 0.f;
        #pragma unroll
        for (int ns = 0; ns < 16; ns++) {
            e[ns] = msk[ns] ? __expf(s[ns] - mx) : 0.f;
            sum += e[ns];
        }
        sum += __shfl_xor(sum, 1);
        sum += __shfl_xor(sum, 2);
        sum += __shfl_xor(sum, 4);
        sum += __shfl_xor(sum, 8);
        float inv = LAM_ATT / sum;
        const size_t mrow = ((size_t)b * NN + q0 + quad * 4 + r) * NN;
        #pragma unroll
        for (int ns = 0; ns < 16; ns++) {
            float p = e[ns] * inv + (float)Mmix[mrow + ns * 16 + cl];
            Ps[(wave * 16 + quad * 4 + r) * 264 + ns * 16 + cl] = __float2bfloat16(p);
        }
    }
    __syncthreads();   // Ps writes complete

    floatx4 accX[4];
    #pragma unroll
    for (int nd = 0; nd < 4; nd++) accX[nd] = (floatx4){0.f, 0.f, 0.f, 0.f};
    #pragma unroll
    for (int ks = 0; ks < 8; ks++) {
        short8 ap = *(const short8*)&Ps[(wave * 16 + cl) * 264 + ks * 32 + quad * 8];
        #pragma unroll
        for (int nd = 0; nd < 4; nd++) {
            const size_t voff = ((size_t)((b * HHc + h) * DKc + nd * 16 + cl)) * NN
                              + ks * 32 + quad * 8;
            short8 bv = *(const short8*)(Vt + voff);
            accX[nd] = __builtin_amdgcn_mfma_f32_16x16x32_bf16(ap, bv, accX[nd], 0, 0, 0);
        }
    }
    #pragma unroll
    for (int nd = 0; nd < 4; nd++) {
        #pragma unroll
        for (int r = 0; r < 4; r++) {
            int row = b * NN + q0 + quad * 4 + r;
            X[(size_t)row * DD + h * DKc + nd * 16 + cl] = __float2bfloat16(accX[nd][r]);
        }
    }
}

// ---------------------------------------------------------------------------
extern "C" void kernel_launch(void* const* d_in, const int* in_sizes, int n_in,
                              void* d_out, int out_size, void* d_ws, size_t ws_size,
                              hipStream_t stream)
{
    const void* query   = d_in[0];
    const void* key     = d_in[1];
    const void* value   = d_in[2];
    const void* adj     = d_in[3];
    const void* dist    = d_in[4];
    const void* maskraw = d_in[6];
    const void* Wq = d_in[7];   const void* bq = d_in[8];
    const void* Wk = d_in[9];   const void* bk = d_in[10];
    const void* Wv = d_in[11];  const void* bv = d_in[12];
    const void* Wo = d_in[13];  const void* bo = d_in[14];

    char* w = (char*)d_ws;
    int* mask_canon = (int*)w;
    int* flags      = (int*)(w + 16384);
    __hip_bfloat16* Wt_all   = (__hip_bfloat16*)(w + 32768);
    __hip_bfloat16* bias_all = (__hip_bfloat16*)(w + 32768 + ((size_t)8 << 20));
    char* base2 = w + 32768 + ((size_t)8 << 20) + 32768;
    const size_t tokElems = (size_t)BB * NN * DD;     // 4,194,304
    __hip_bfloat16* Qc   = (__hip_bfloat16*)base2;    // bf16 activations
    __hip_bfloat16* Kc   = Qc + tokElems;
    __hip_bfloat16* Vc   = Kc + tokElems;
    __hip_bfloat16* Qp   = Vc + tokElems;
    __hip_bfloat16* Kp   = Qp + tokElems;
    __hip_bfloat16* Vt   = Kp + tokElems;
    __hip_bfloat16* Mmix = Vt + tokElems;             // 1M elems (2MB)
    __hip_bfloat16* X    = Qc;                        // reuse: Qc dead after qkv

    detect_kernel<<<1, 256, 0, stream>>>(query, maskraw, mask_canon, flags);

    prep_mega<<<8196, 256, 0, stream>>>(query, key, value, adj, dist,
                                        Wq, Wk, Wv, Wo, bq, bk, bv, bo,
                                        mask_canon, flags,
                                        Wt_all, bias_all, Mmix, Qc, Kc, Vc);

    qkv_mfma<<<768, 256, 0, stream>>>(Qc, Kc, Vc, Wt_all, bias_all, Qp, Kp, Vt);

    attn_mfma<<<1024, 256, 0, stream>>>(Qp, Kp, Vt, Mmix, mask_canon, X);

    out_mfma<<<512, 256, 0, stream>>>(X, Wt_all + (size_t)3 * DD * DD,
                                      bias_all + 3 * DD, d_out, flags);
}